// Round 1
// 179.466 us; speedup vs baseline: 1.0620x; 1.0620x over previous
//
#include <hip/hip_runtime.h>
#include <math.h>

#define NEAR0f 1e-8f
#define REGf   0.002f

typedef float __attribute__((ext_vector_type(4))) f32x4;
typedef int   __attribute__((ext_vector_type(4))) i32x4;

__device__ __forceinline__ float wave_reduce(float v) {
#pragma unroll
    for (int off = 32; off > 0; off >>= 1)
        v += __shfl_down(v, off, 64);
    return v;
}

// sum of log(selected prob) over 4 elements, tree-summed
__device__ __forceinline__ float nll4(f32x4 p, i32x4 l) {
    float a0 = l.x ? p.x : 1.0f - p.x;
    float a1 = l.y ? p.y : 1.0f - p.y;
    float a2 = l.z ? p.z : 1.0f - p.z;
    float a3 = l.w ? p.w : 1.0f - p.w;
    float g0 = __logf(fmaxf(a0, NEAR0f)) + __logf(fmaxf(a1, NEAR0f));
    float g1 = __logf(fmaxf(a2, NEAR0f)) + __logf(fmaxf(a3, NEAR0f));
    return g0 + g1;
}

__device__ __forceinline__ float sq4(f32x4 a, float acc) {
    return fmaf(a.x, a.x, fmaf(a.y, a.y, fmaf(a.z, a.z, fmaf(a.w, a.w, acc))));
}

// R0: latency-bound diagnosis (17.7% HBM, 13% VALU, 22% occ).
//  - grid 1024 -> 2048 blocks (8 blocks/CU = 32 waves/CU max; launch_bounds
//    (256,8) caps VGPR at 64, we were at 32). Exact fit: 8 p-elems + 2 w-elems
//    per thread, no tail.
//  - nontemporal loads removed: working set (160 MiB) < 256 MiB L3, but nt
//    evict-first hints were forcing ~half (80 MiB FETCH_SIZE) back to HBM
//    every dispatch.
//  - per-block partials instead of atomics: kills the init_acc launch
//    (poison-safe: every slot is fully written each launch before being read).
__global__ __launch_bounds__(256, 8) void reduce_all(
    const f32x4* __restrict__ p4,
    const i32x4* __restrict__ l4,
    const f32x4* __restrict__ w1,
    const f32x4* __restrict__ w2,
    float* __restrict__ part,
    int n4, int w4)
{
    const int tid    = blockIdx.x * blockDim.x + threadIdx.x;
    const int stride = gridDim.x * blockDim.x;

    float nll0 = 0.0f, nll1 = 0.0f, nll2 = 0.0f, nll3 = 0.0f;
    int i = tid;
    for (; i + 3 * stride < n4; i += 4 * stride) {
        f32x4 p0 = p4[i];
        f32x4 p1 = p4[i + stride];
        f32x4 p2 = p4[i + 2 * stride];
        f32x4 p3 = p4[i + 3 * stride];
        i32x4 l0 = l4[i];
        i32x4 l1 = l4[i + stride];
        i32x4 l2 = l4[i + 2 * stride];
        i32x4 l3 = l4[i + 3 * stride];
        nll0 -= nll4(p0, l0);
        nll1 -= nll4(p1, l1);
        nll2 -= nll4(p2, l2);
        nll3 -= nll4(p3, l3);
    }
    for (; i < n4; i += stride) {
        nll0 -= nll4(p4[i], l4[i]);
    }
    float nll = (nll0 + nll1) + (nll2 + nll3);

    float s1a = 0.0f, s1b = 0.0f, s2a = 0.0f, s2b = 0.0f;
    int j = tid;
    for (; j + stride < w4; j += 2 * stride) {
        f32x4 a0 = w1[j];
        f32x4 a1 = w1[j + stride];
        f32x4 b0 = w2[j];
        f32x4 b1 = w2[j + stride];
        s1a = sq4(a0, s1a); s1b = sq4(a1, s1b);
        s2a = sq4(b0, s2a); s2b = sq4(b1, s2b);
    }
    for (; j < w4; j += stride) {
        s1a = sq4(w1[j], s1a);
        s2a = sq4(w2[j], s2a);
    }
    float s1 = s1a + s1b;
    float s2 = s2a + s2b;

    nll = wave_reduce(nll);
    s1  = wave_reduce(s1);
    s2  = wave_reduce(s2);

    __shared__ float sm[3][4];
    const int lane = threadIdx.x & 63;
    const int wave = threadIdx.x >> 6;
    if (lane == 0) { sm[0][wave] = nll; sm[1][wave] = s1; sm[2][wave] = s2; }
    __syncthreads();
    if (threadIdx.x == 0) {
        f32x4 o;
        o.x = sm[0][0] + sm[0][1] + sm[0][2] + sm[0][3];
        o.y = sm[1][0] + sm[1][1] + sm[1][2] + sm[1][3];
        o.z = sm[2][0] + sm[2][1] + sm[2][2] + sm[2][3];
        o.w = 0.0f;
        *(f32x4*)(part + (size_t)blockIdx.x * 4) = o;  // 16B aligned slot
    }
}

// Reduce per-block partials, apply mean + regularizer. One block, 256 threads.
__global__ void finalize(const float* __restrict__ part, float* __restrict__ out,
                         float invN, int nblocks) {
    float nll = 0.0f, s1 = 0.0f, s2 = 0.0f;
    for (int i = threadIdx.x; i < nblocks; i += 256) {
        const f32x4 v = *(const f32x4*)(part + (size_t)i * 4);
        nll += v.x; s1 += v.y; s2 += v.z;
    }
    nll = wave_reduce(nll);
    s1  = wave_reduce(s1);
    s2  = wave_reduce(s2);

    __shared__ float sm[3][4];
    const int lane = threadIdx.x & 63;
    const int wave = threadIdx.x >> 6;
    if (lane == 0) { sm[0][wave] = nll; sm[1][wave] = s1; sm[2][wave] = s2; }
    __syncthreads();
    if (threadIdx.x == 0) {
        float tn = sm[0][0] + sm[0][1] + sm[0][2] + sm[0][3];
        float t1 = sm[1][0] + sm[1][1] + sm[1][2] + sm[1][3];
        float t2 = sm[2][0] + sm[2][1] + sm[2][2] + sm[2][3];
        out[0] = tn * invN + REGf * (sqrtf(t1) + sqrtf(t2));
    }
}

extern "C" void kernel_launch(void* const* d_in, const int* in_sizes, int n_in,
                              void* d_out, int out_size, void* d_ws, size_t ws_size,
                              hipStream_t stream) {
    const float* out1  = (const float*)d_in[0];   // [N,1] fp32
    const int*   label = (const int*)d_in[1];     // [N] int32 (jax default x64-off)
    const float* W1    = (const float*)d_in[2];   // [1024,4096] fp32
    const float* W2    = (const float*)d_in[3];   // [4096,1024] fp32

    const int N  = in_sizes[0];
    const int n4 = N / 4;
    const int w4 = in_sizes[2] / 4;               // W1 and W2 same size

    const int NBLK = 2048;                        // 8 blocks/CU, 32 waves/CU
    float* part = (float*)d_ws;                   // NBLK * 4 floats = 32 KB

    reduce_all<<<NBLK, 256, 0, stream>>>(
        (const f32x4*)out1, (const i32x4*)label,
        (const f32x4*)W1,   (const f32x4*)W2,
        part, n4, w4);
    finalize<<<1, 256, 0, stream>>>(part, (float*)d_out, 1.0f / (float)N, NBLK);
}